// Round 2
// baseline (317.619 us; speedup 1.0000x reference)
//
#include <hip/hip_runtime.h>
#include <hip/hip_bf16.h>

typedef __attribute__((ext_vector_type(8))) short short8;
typedef __attribute__((ext_vector_type(4))) float f32x4;
typedef __attribute__((ext_vector_type(2))) float f32x2;

// X: (32, 256, 64, 64) f32 ; W,B: (256, 256, 2, 2) f32 ; out: (32, 256, 128, 128) f32
// GEMM view: M = 131072 pixels, N = 1024 (col = o*4 + kh*2 + kw), K = 256.

__device__ __forceinline__ short f2bf(float f) {
    union { __hip_bfloat16 h; short s; } u; u.h = __float2bfloat16(f); return u.s;
}

// bsum[o*4+kl] = sum_c biases[o][c][kl]
__global__ __launch_bounds__(64) void prep_bias(const float* __restrict__ B, float* __restrict__ bsum) {
    const int o = blockIdx.x;
    const int t = threadIdx.x;
    float acc0 = 0.f, acc1 = 0.f, acc2 = 0.f, acc3 = 0.f;
    for (int c = t; c < 256; c += 64) {
        f32x4 v = *(const f32x4*)(B + ((size_t)o << 10) + ((size_t)c << 2));
        acc0 += v[0]; acc1 += v[1]; acc2 += v[2]; acc3 += v[3];
    }
    #pragma unroll
    for (int off = 32; off >= 1; off >>= 1) {
        acc0 += __shfl_down(acc0, off, 64);
        acc1 += __shfl_down(acc1, off, 64);
        acc2 += __shfl_down(acc2, off, 64);
        acc3 += __shfl_down(acc3, off, 64);
    }
    if (t == 0) {
        bsum[(o << 2) + 0] = acc0;
        bsum[(o << 2) + 1] = acc1;
        bsum[(o << 2) + 2] = acc2;
        bsum[(o << 2) + 3] = acc3;
    }
}

// Block tile: BM=128 x BN=256, BK=64, 8 waves (2x4), wave tile 64x64.
// A and B both staged as bf16 [row][k] (k-contiguous, pad 64->72) so all
// fragment reads are conflict-free ds_read_b128.
__global__ __launch_bounds__(512, 4) void deconv_gemm(
    const float* __restrict__ X, const float* __restrict__ W,
    const float* __restrict__ Bsum, float* __restrict__ Y)
{
    __shared__ short As[128][72];   // bf16 A^T tile: [m][k], row 144 B
    __shared__ short Bs[256][72];   // bf16 B tile:  [col][k], row 144 B

    const int tid = threadIdx.x;
    int bid = blockIdx.x;
    bid = ((bid & 7) << 9) | (bid >> 3);   // XCD-chunked swizzle (4096 = 8*512, bijective)
    const int cb  = bid & 3;        // col tile (4 col-blocks sharing an A tile are consecutive)
    const int rb  = bid >> 2;
    const int p0  = rb << 7;        // pixel base
    const int n   = p0 >> 12;       // image
    const int q0  = p0 & 4095;      // pixel within image
    const int o0  = cb << 6;        // o base

    const int wave = tid >> 6, lane = tid & 63;
    const int wm = wave >> 2, wn = wave & 3;    // 2x4 wave grid
    const int l15 = lane & 15, g = lane >> 4;

    f32x4 acc[4][4] = {};

    // A staging: thread owns rows m = 2*mp, 2*mp+1 for k = kb..kb+7
    const int mp = tid & 63;
    const int kb = wave << 3;
    const float* xp = X + ((size_t)n << 20) + ((size_t)kb << 12) + (size_t)(q0 + (mp << 1));
    // B staging: thread owns cols ol*4+kl (kl=0..3) for k = t7*8..t7*8+7
    const int ol = tid >> 3, t7 = tid & 7;
    const float* wp = W + ((size_t)(o0 + ol) << 10) + (size_t)(t7 << 5);

    for (int c0 = 0; c0 < 256; c0 += 64) {
        // global loads for this K-tile (issued before the barrier -> latency
        // overlaps barrier wait + other block's compute)
        f32x2 av[8];
        #pragma unroll
        for (int j = 0; j < 8; ++j)
            av[j] = *(const f32x2*)(xp + ((size_t)(c0 + j) << 12));
        f32x4 bv[8];
        #pragma unroll
        for (int q = 0; q < 8; ++q)
            bv[q] = *(const f32x4*)(wp + (c0 << 2) + (q << 2));

        __syncthreads();   // previous tile fully consumed

        #pragma unroll
        for (int r = 0; r < 2; ++r) {
            short8 sv;
            #pragma unroll
            for (int j = 0; j < 8; ++j) sv[j] = f2bf(av[j][r]);
            *(short8*)&As[(mp << 1) + r][kb] = sv;
        }
        #pragma unroll
        for (int kl = 0; kl < 4; ++kl) {
            short8 sv;
            #pragma unroll
            for (int q = 0; q < 8; ++q) sv[q] = f2bf(bv[q][kl]);
            *(short8*)&Bs[(ol << 2) + kl][t7 << 3] = sv;
        }

        __syncthreads();   // tile visible

        #pragma unroll
        for (int ks = 0; ks < 2; ++ks) {
            short8 afr[4], bfr[4];
            #pragma unroll
            for (int fn = 0; fn < 4; ++fn)
                bfr[fn] = *(const short8*)&Bs[(wn << 6) + (fn << 4) + l15][(ks << 5) + (g << 3)];
            #pragma unroll
            for (int fm = 0; fm < 4; ++fm)
                afr[fm] = *(const short8*)&As[(wm << 6) + (fm << 4) + l15][(ks << 5) + (g << 3)];
            #pragma unroll
            for (int fm = 0; fm < 4; ++fm) {
                #pragma unroll
                for (int fn = 0; fn < 4; ++fn)
                    acc[fm][fn] = __builtin_amdgcn_mfma_f32_16x16x32_bf16(afr[fm], bfr[fn], acc[fm][fn], 0, 0, 0);
            }
        }
    }

    // Epilogue (verified in round 1): frag (r) -> pixel = wm*64+fm*16+4g+r,
    // col = cb*256 + wn*64 + fn*16 + l15. Pair-swap lane^1 merges kw=0/1 so
    // each lane stores one contiguous float4.
    const int ih = (q0 >> 6) + wm;
    #pragma unroll
    for (int fn = 0; fn < 4; ++fn) {
        const int col = (cb << 8) + (wn << 6) + (fn << 4) + l15;
        const float bv = Bsum[col];
        const int o = col >> 2;
        const int h = (ih << 1) + ((col >> 1) & 1);
        float* yrow = Y + ((((size_t)n << 8) + (size_t)o) << 14) + ((size_t)h << 7);
        #pragma unroll
        for (int fm = 0; fm < 4; ++fm) {
            const float v0 = acc[fm][fn][0] + bv;
            const float v1 = acc[fm][fn][1] + bv;
            const float v2 = acc[fm][fn][2] + bv;
            const float v3 = acc[fm][fn][3] + bv;
            const float p0v = __shfl_xor(v0, 1, 64);
            const float p1v = __shfl_xor(v1, 1, 64);
            const float p2v = __shfl_xor(v2, 1, 64);
            const float p3v = __shfl_xor(v3, 1, 64);
            const int iw0 = (fm << 4) + (g << 2);
            f32x4 st; int w;
            if (!(lane & 1)) { st = (f32x4){v0, p0v, v1, p1v}; w = (iw0 << 1); }
            else             { st = (f32x4){p2v, v2, p3v, v3}; w = (iw0 << 1) + 4; }
            *(f32x4*)(yrow + w) = st;
        }
    }
}

extern "C" void kernel_launch(void* const* d_in, const int* in_sizes, int n_in,
                              void* d_out, int out_size, void* d_ws, size_t ws_size,
                              hipStream_t stream) {
    const float* X = (const float*)d_in[0];   // batches (32,256,64,64)
    const float* W = (const float*)d_in[1];   // weights (256,256,2,2)
    const float* B = (const float*)d_in[2];   // biases  (256,256,2,2)
    float* bsum = (float*)d_ws;               // 4 KiB scratch
    prep_bias<<<256, 64, 0, stream>>>(B, bsum);
    deconv_gemm<<<4096, 512, 0, stream>>>(X, W, bsum, (float*)d_out);
}